// Round 22
// baseline (730.250 us; speedup 1.0000x reference)
//
#include <hip/hip_runtime.h>
#include <hip/hip_bf16.h>
#include <math.h>

// ---------------------------------------------------------------------------
// CrossAttentionBlock on MI355X (gfx950) — round 21: final traffic cuts on
// the r20 base (724 µs): (1) SA-proj residual read from XB (bf16, 16 MB)
// instead of x (f32, 33 MB) — XB is live until step 7; (2) V^T epilogue
// stores via truncation (V feeds only PV MFMA). Rest identical to r20.
// B=4 N=2048 M=1024 C=1024 H=16 HD=64 HID=4096
// ---------------------------------------------------------------------------

typedef __attribute__((ext_vector_type(8))) short bf16x8;   // 8 bf16 in 4 VGPRs
typedef __attribute__((ext_vector_type(4))) short s16x4;    // 4 bf16 (8B)
typedef __attribute__((ext_vector_type(4))) float f32x4;

#define DEV __device__ __forceinline__

DEV unsigned short f2us(float f) {
  __hip_bfloat16 h = __float2bfloat16(f);
  return __builtin_bit_cast(unsigned short, h);
}

DEV short f2us_trunc(float f) {
  return (short)(__builtin_bit_cast(unsigned, f) >> 16);
}

DEV void gload_lds16(const void* g, void* l) {
  __builtin_amdgcn_global_load_lds((const __attribute__((address_space(1))) void*)g,
                                   (__attribute__((address_space(3))) void*)l, 16, 0, 0);
}

#define MFMA_BF16_16x16x32 __builtin_amdgcn_mfma_f32_16x16x32_bf16
#define WAITV0 asm volatile("s_waitcnt vmcnt(0)" ::: "memory")

// ------------------------- elementwise converts ----------------------------

__global__ __launch_bounds__(256) void cvt_f32_bf16(const float* __restrict__ in,
                                                    __hip_bfloat16* __restrict__ out,
                                                    long n) {
  long i = ((long)blockIdx.x * blockDim.x + threadIdx.x) * 4;
  if (i + 3 < n) {
    float4 v = *(const float4*)(in + i);
    out[i + 0] = __float2bfloat16(v.x);
    out[i + 1] = __float2bfloat16(v.y);
    out[i + 2] = __float2bfloat16(v.z);
    out[i + 3] = __float2bfloat16(v.w);
  }
}

// w (K,N) fp32 row-major -> wT (N,K) bf16 row-major
__global__ __launch_bounds__(256) void transpose_cvt(const float* __restrict__ w,
                                                     __hip_bfloat16* __restrict__ wT,
                                                     int K, int N) {
  __shared__ float tile[32][33];
  int n0 = blockIdx.x * 32, k0 = blockIdx.y * 32;
  int tx = threadIdx.x, ty = threadIdx.y;
  #pragma unroll
  for (int i = 0; i < 32; i += 8)
    tile[ty + i][tx] = w[(long)(k0 + ty + i) * N + n0 + tx];
  __syncthreads();
  #pragma unroll
  for (int i = 0; i < 32; i += 8)
    wT[(long)(n0 + ty + i) * K + k0 + tx] = __float2bfloat16(tile[tx][ty + i]);
}

// w (1024, 4096) fp32 -> interleaved-transposed bf16: source col j goes to
// output row r = 32*(j>>4) + (j&15) + ofs  (ofs=0 for w1g, 16 for w1x).
__global__ __launch_bounds__(256) void transpose_cvt_ilv(const float* __restrict__ w,
                                                         __hip_bfloat16* __restrict__ wI,
                                                         int K, int N, int ofs) {
  __shared__ float tile[32][33];
  int n0 = blockIdx.x * 32, k0 = blockIdx.y * 32;
  int tx = threadIdx.x, ty = threadIdx.y;
  #pragma unroll
  for (int i = 0; i < 32; i += 8)
    tile[ty + i][tx] = w[(long)(k0 + ty + i) * N + n0 + tx];
  __syncthreads();
  #pragma unroll
  for (int i = 0; i < 32; i += 8) {
    int j = n0 + ty + i;
    int r = 32 * (j >> 4) + (j & 15) + ofs;
    wI[(long)r * K + k0 + tx] = __float2bfloat16(tile[tx][ty + i]);
  }
}

// --------------------- epilogue helper (simple EPIs) -----------------------
// EPI 1: out_b = bf16( scale*(v+bias) + bf16(mulin) )        (sa proj, resid=XB)
// EPI 2: out_b = bf16( scale*((v+bias)*tanh(gate)) + bf16(mulin) )  (ca proj)
// EPI 5: out_f = scale*(v+bias) + bf16(mulin)                 (final, f32 out)
template <int EPI>
DEV void epi_store(long idx, long col, float v,
                   float* __restrict__ out_f, __hip_bfloat16* __restrict__ out_b,
                   const float* __restrict__ bias, const float* __restrict__ scale,
                   const float* __restrict__ gate, const float* __restrict__ resid,
                   const __hip_bfloat16* __restrict__ mulin) {
  if constexpr (EPI == 0) {
    out_b[idx] = __float2bfloat16(v);
  } else if constexpr (EPI == 1) {
    float r = scale[col] * (v + bias[col]) + __bfloat162float(mulin[idx]);
    out_b[idx] = __float2bfloat16(r);
  } else if constexpr (EPI == 2) {
    float r = scale[col] * ((v + bias[col]) * tanhf(gate[col])) + __bfloat162float(mulin[idx]);
    out_b[idx] = __float2bfloat16(r);
  } else {  // EPI == 5
    out_f[idx] = scale[col] * (v + bias[col]) + __bfloat162float(mulin[idx]);
  }
}

// --------------- GEMM BMx256, BK=64, 2-phase (T3 minimum, r5) --------------
// EPI=6: fused SwiGLU over 16-wide interleaved W1I cols (out ld N/2).
// EPI=8 (qkv): slice0=q LN+rope, slice1=k LN+rope, slice2=v -> swizzled V^T
//              tiled store (vt via mulin, 8192B tiles, granule ^= drow&7).
// EPI=9 (ca_q): LN+rope. EPI=10 (kvc): slice0=K LN no rope, slice1=V -> V^T.
template <int BM, int EPI>
__global__ __launch_bounds__(512, 2) void gemm2ph(const __hip_bfloat16* __restrict__ A,
                                                  const __hip_bfloat16* __restrict__ Bt,
                                                  int M, int N, int K,
                                                  float* __restrict__ out_f,
                                                  __hip_bfloat16* __restrict__ out_b,
                                                  const float* __restrict__ bias,
                                                  const float* __restrict__ scale,
                                                  const float* __restrict__ gate,
                                                  const float* __restrict__ resid,
                                                  const __hip_bfloat16* __restrict__ mulin) {
  constexpr int MF = BM / 32;
  constexpr int WRS = BM / 2;
  constexpr int AJ = BM * 8 / 512;
  __shared__ __align__(16) unsigned short As[2][BM * 64];
  __shared__ __align__(16) unsigned short Bs[2][256 * 64];

  int t = threadIdx.x;
  int l = t & 63, w = t >> 6;
  int lo = l & 15, hi = l >> 4;
  int wr = w >> 2, wc = w & 3;
  long bm = blockIdx.x, bn = blockIdx.y;
  const __hip_bfloat16* Ab = A + bm * BM * (long)K;
  const __hip_bfloat16* Bb = Bt + bn * 256 * (long)K;
  int nt = K >> 6;

  auto stage = [&](int kt, int buf) {
    long kb = (long)kt * 64;
    #pragma unroll
    for (int j = 0; j < AJ; j++) {
      int q = j * 512 + t;
      int row = q >> 3, c = (q & 7) ^ (row & 7);
      gload_lds16(Ab + (long)row * K + kb + c * 8, &As[buf][q * 8]);
    }
    #pragma unroll
    for (int j = 0; j < 4; j++) {
      int q = j * 512 + t;
      int row = q >> 3, c = (q & 7) ^ (row & 7);
      gload_lds16(Bb + (long)row * K + kb + c * 8, &Bs[buf][q * 8]);
    }
  };

  f32x4 acc[MF][4] = {};

  stage(0, 0);
  WAITV0;
  __builtin_amdgcn_s_barrier();

  for (int kt = 0; kt < nt; ++kt) {
    int cur = kt & 1;
    if (kt + 1 < nt) stage(kt + 1, cur ^ 1);

    #pragma unroll
    for (int ks = 0; ks < 2; ks++) {
      bf16x8 bfrag[4];
      #pragma unroll
      for (int n = 0; n < 4; n++) {
        int rb = wc * 64 + n * 16 + lo;
        bfrag[n] = *(const bf16x8*)&Bs[cur][rb * 64 + (((ks << 2) | hi) ^ (rb & 7)) * 8];
      }
      #pragma unroll
      for (int mg = 0; mg < MF; mg += 4) {
        bf16x8 afrag[4];
        #pragma unroll
        for (int m = 0; m < 4; m++) {
          int ra = wr * WRS + (mg + m) * 16 + lo;
          afrag[m] = *(const bf16x8*)&As[cur][ra * 64 + (((ks << 2) | hi) ^ (ra & 7)) * 8];
        }
        __builtin_amdgcn_s_setprio(1);
        #pragma unroll
        for (int m = 0; m < 4; m++)
          #pragma unroll
          for (int n = 0; n < 4; n++)
            acc[mg + m][n] = MFMA_BF16_16x16x32(afrag[m], bfrag[n], acc[mg + m][n], 0, 0, 0);
        __builtin_amdgcn_s_setprio(0);
      }
    }

    if (kt + 1 < nt) {
      WAITV0;
      __builtin_amdgcn_s_barrier();
    }
  }

  if constexpr (EPI == 6) {
    #pragma unroll
    for (int m = 0; m < MF; m++)
      #pragma unroll
      for (int np = 0; np < 2; np++)
        #pragma unroll
        for (int i = 0; i < 4; i++) {
          long row = bm * BM + wr * WRS + m * 16 + hi * 4 + i;
          long jc = bn * 128 + wc * 32 + np * 16 + lo;
          float g = acc[m][np * 2][i] + bias[jc];
          float xv = acc[m][np * 2 + 1][i] + gate[jc];
          float hv = (g / (1.f + expf(-g))) * xv;
          out_b[row * (long)(N >> 1) + jc] = __float2bfloat16(hv);
        }
  } else if constexpr (EPI == 8 || EPI == 9 || EPI == 10) {
    int colbase = (int)(bn * 256 + wc * 64);   // wave-uniform; spans one head
    int slice = colbase >> 10;
    bool dovt = (EPI == 8 && slice == 2) || (EPI == 10 && slice == 1);
    if (dovt) {
      // Swizzled V^T tiled store: [b*16+h][kvtile][drow=nn*16+lo][64 shorts],
      // 16B granule gk=2m+(hi>>1) ^ (drow&7), 8B half = hi&1.
      unsigned short* vt = (unsigned short*)mulin;
      int h = (colbase >> 6) & 15;
      int kvt = (EPI == 8) ? ((int)(bm & 15) * 2 + wr) : ((int)(bm & 7) * 2 + wr);
      constexpr int NTV = (EPI == 8) ? 32 : 16;
      #pragma unroll
      for (int m = 0; m < MF; m++) {
        long row0 = bm * BM + wr * WRS + m * 16 + hi * 4;   // i=0 token row
        int b = (int)(row0 >> ((EPI == 8) ? 11 : 10));
        long tb = ((long)(b * 16 + h) * NTV + kvt) * 4096;  // 8192B tiles
        int gk = 2 * m + (hi >> 1);
        #pragma unroll
        for (int nn = 0; nn < 4; nn++) {
          int drow = nn * 16 + lo;
          s16x4 pw;
          pw[0] = f2us_trunc(acc[m][nn][0]);
          pw[1] = f2us_trunc(acc[m][nn][1]);
          pw[2] = f2us_trunc(acc[m][nn][2]);
          pw[3] = f2us_trunc(acc[m][nn][3]);
          long off = tb + (long)drow * 64 + (((gk ^ (drow & 7)) << 3) | ((hi & 1) << 2));
          *(s16x4*)&vt[off] = pw;
        }
      }
    } else {
      const float *gv_p, *bv_p;
      if constexpr (EPI == 8) {
        gv_p = (slice == 0) ? bias : gate;       // sa_qg : sa_kg
        bv_p = (slice == 0) ? scale : resid;     // sa_qb : sa_kb
      } else if constexpr (EPI == 9) {
        gv_p = bias; bv_p = scale;               // ca_qg, ca_qb
      } else {
        gv_p = bias; bv_p = scale;               // ca_kg, ca_kb (slice 0)
      }
      float gv[4], bv[4];
      #pragma unroll
      for (int nn = 0; nn < 4; nn++) {
        gv[nn] = gv_p[nn * 16 + lo];
        bv[nn] = bv_p[nn * 16 + lo];
      }
      #pragma unroll
      for (int m = 0; m < MF; m++)
        #pragma unroll
        for (int i = 0; i < 4; i++) {
          float v0 = acc[m][0][i], v1 = acc[m][1][i], v2 = acc[m][2][i], v3 = acc[m][3][i];
          float s = (v0 + v1) + (v2 + v3);
          s += __shfl_xor(s, 1); s += __shfl_xor(s, 2);
          s += __shfl_xor(s, 4); s += __shfl_xor(s, 8);
          float mean = s * 0.015625f;
          float d0 = v0 - mean, d1 = v1 - mean, d2 = v2 - mean, d3 = v3 - mean;
          float q2 = (d0 * d0 + d1 * d1) + (d2 * d2 + d3 * d3);
          q2 += __shfl_xor(q2, 1); q2 += __shfl_xor(q2, 2);
          q2 += __shfl_xor(q2, 4); q2 += __shfl_xor(q2, 8);
          float rstd = rsqrtf(q2 * 0.015625f + 1e-6f);
          long row = bm * BM + wr * WRS + m * 16 + hi * 4 + i;
          int nseq = (int)(row & 2047);        // rows = b*2048 + n (M=8192)
          float xsv[4] = {d0 * rstd, d1 * rstd, d2 * rstd, d3 * rstd};
          #pragma unroll
          for (int nn = 0; nn < 4; nn++) {
            float xn = xsv[nn] * gv[nn] + bv[nn];
            if constexpr (EPI != 10) {         // rope (EPI 8/9)
              float partner = __shfl_xor(xn, 1);
              int d = nn * 16 + lo;
              float sn = out_f[(long)nseq * 128 + d];
              float cs = out_f[(long)nseq * 128 + 64 + d];
              xn = (lo & 1) ? (xn * cs + partner * sn) : (xn * cs - partner * sn);
            }
            out_b[row * (long)N + colbase + nn * 16 + lo] = __float2bfloat16(xn);
          }
        }
    }
  } else {
    #pragma unroll
    for (int m = 0; m < MF; m++)
      #pragma unroll
      for (int n = 0; n < 4; n++)
        #pragma unroll
        for (int i = 0; i < 4; i++) {
          long row = bm * BM + wr * WRS + m * 16 + hi * 4 + i;
          long col = bn * 256 + wc * 64 + n * 16 + lo;
          epi_store<EPI>(row * (long)N + col, col, acc[m][n][i],
                         out_f, out_b, bias, scale, gate, resid, mulin);
        }
  }
}

// ---------------------------- attention ------------------------------------
// r7 structure + T5 setprio; V^T and P in the GEMM-proven swizzled layout
// (64-short rows, 16B granule ^= row&7 -> ~0 ds_read conflicts).
__global__ __launch_bounds__(256) void attn32(const __hip_bfloat16* __restrict__ qB, long qBatch, long qRow,
                                              const __hip_bfloat16* __restrict__ kB, long kBatch, long kRow,
                                              const __hip_bfloat16* __restrict__ vt,
                                              __hip_bfloat16* __restrict__ out, int Nq, int Nkv) {
  const float SC2 = 0.125f * 1.44269504089f;
  int t = threadIdx.x;
  int l = t & 63, w = t >> 6;
  int lo = l & 15, hi = l >> 4;
  int nQC = Nq >> 7;
  int qc = blockIdx.x % nQC;
  int bh = blockIdx.x / nQC;
  int h = bh & 15, b = bh >> 4;
  int q0 = qc * 128 + w * 32;

  __shared__ unsigned short P_all[4][32 * 64];   // swizzled, per-wave
  __shared__ unsigned short V_lds[2][64 * 64];   // swizzled tile copy
  unsigned short* P = P_all[w];

  bf16x8 qf[2][2];
#pragma unroll
  for (int qs = 0; qs < 2; qs++) {
    const __hip_bfloat16* qp = qB + (long)b * qBatch + (long)(q0 + qs * 16 + lo) * qRow + h * 64 + hi * 8;
    qf[qs][0] = *(const bf16x8*)qp;
    qf[qs][1] = *(const bf16x8*)(qp + 32);
  }

  float mrow[2] = {-INFINITY, -INFINITY};
  float lsum[2] = {0.f, 0.f};
  f32x4 acc[2][4] = {};
  const f32x4 fz = {0.f, 0.f, 0.f, 0.f};

  const __hip_bfloat16* kbase = kB + (long)b * kBatch + h * 64 + hi * 8;
  int nt = Nkv >> 6;
  const char* vtb = (const char*)vt + (long)bh * nt * 8192;

  auto stageV = [&](int tile, unsigned short* dstb) {
    const char* src = vtb + (long)tile * 8192;
    gload_lds16(src + t * 16, &dstb[t * 8]);
    gload_lds16(src + (t + 256) * 16, &dstb[(t + 256) * 8]);
  };
  auto loadK = [&](int tile, bf16x8 (&kg)[4][2]) {
#pragma unroll
    for (int g = 0; g < 4; g++) {
      const __hip_bfloat16* kp = kbase + (long)(tile * 64 + g * 16 + lo) * kRow;
      kg[g][0] = *(const bf16x8*)kp;
      kg[g][1] = *(const bf16x8*)(kp + 32);
    }
  };
  auto qkt = [&](bf16x8 (&kg)[4][2], f32x4 (&ST)[2][4]) {
    __builtin_amdgcn_s_setprio(1);
#pragma unroll
    for (int qs = 0; qs < 2; qs++)
#pragma unroll
      for (int g = 0; g < 4; g++) {
        f32x4 s0 = MFMA_BF16_16x16x32(kg[g][0], qf[qs][0], fz, 0, 0, 0);
        ST[qs][g] = MFMA_BF16_16x16x32(kg[g][1], qf[qs][1], s0, 0, 0, 0);
      }
    __builtin_amdgcn_s_setprio(0);
  };
  auto smax = [&](f32x4 (&ST)[2][4]) {
#pragma unroll
    for (int qs = 0; qs < 2; qs++) {
      float mg0 = fmaxf(fmaxf(ST[qs][0][0], ST[qs][0][1]), fmaxf(ST[qs][0][2], ST[qs][0][3]));
      float mg1 = fmaxf(fmaxf(ST[qs][1][0], ST[qs][1][1]), fmaxf(ST[qs][1][2], ST[qs][1][3]));
      float mg2 = fmaxf(fmaxf(ST[qs][2][0], ST[qs][2][1]), fmaxf(ST[qs][2][2], ST[qs][2][3]));
      float mg3 = fmaxf(fmaxf(ST[qs][3][0], ST[qs][3][1]), fmaxf(ST[qs][3][2], ST[qs][3][3]));
      float rm = fmaxf(fmaxf(mg0, mg1), fmaxf(mg2, mg3)) * SC2;
      rm = fmaxf(rm, __shfl_xor(rm, 16));
      rm = fmaxf(rm, __shfl_xor(rm, 32));
      if (!__all(rm <= mrow[qs] + 8.f)) {     // defer-max (T13)
        float mn = fmaxf(mrow[qs], rm);
        float scl = exp2f(mrow[qs] - mn);
        mrow[qs] = mn;
        lsum[qs] *= scl;
        float c0 = __shfl(scl, hi * 4 + 0);
        float c1 = __shfl(scl, hi * 4 + 1);
        float c2 = __shfl(scl, hi * 4 + 2);
        float c3 = __shfl(scl, hi * 4 + 3);
#pragma unroll
        for (int tt = 0; tt < 4; tt++) {
          acc[qs][tt][0] *= c0; acc[qs][tt][1] *= c1;
          acc[qs][tt][2] *= c2; acc[qs][tt][3] *= c3;
        }
      }
      float m = mrow[qs];
      float rs = 0.f;
      int qrow = qs * 16 + lo;
      int sw = lo & 7;
#pragma unroll
      for (int g = 0; g < 4; g++) {
        float p0 = exp2f(fmaf(ST[qs][g][0], SC2, -m));
        float p1 = exp2f(fmaf(ST[qs][g][1], SC2, -m));
        float p2 = exp2f(fmaf(ST[qs][g][2], SC2, -m));
        float p3 = exp2f(fmaf(ST[qs][g][3], SC2, -m));
        rs += (p0 + p1) + (p2 + p3);
        s16x4 pw;
        pw[0] = f2us_trunc(p0); pw[1] = f2us_trunc(p1);
        pw[2] = f2us_trunc(p2); pw[3] = f2us_trunc(p3);
        int gk = 2 * g + (hi >> 1);
        *(s16x4*)&P[qrow * 64 + (((gk ^ sw) << 3) | ((hi & 1) << 2))] = pw;
      }
      rs += __shfl_xor(rs, 16);
      rs += __shfl_xor(rs, 32);
      lsum[qs] += rs;
    }
  };
  auto pv = [&](const unsigned short* Vb) {
    bf16x8 pf[2][2];
    int sw = lo & 7;
#pragma unroll
    for (int qs = 0; qs < 2; qs++) {
      int qrow = qs * 16 + lo;
      pf[qs][0] = *(const bf16x8*)&P[qrow * 64 + ((hi ^ sw) << 3)];
      pf[qs][1] = *(const bf16x8*)&P[qrow * 64 + (((4 | hi) ^ sw) << 3)];
    }
    __builtin_amdgcn_s_setprio(1);
#pragma unroll
    for (int tt = 0; tt < 4; tt++) {
      int drow = tt * 16 + lo;
      bf16x8 v0 = *(const bf16x8*)&Vb[drow * 64 + ((hi ^ sw) << 3)];
      bf16x8 v1 = *(const bf16x8*)&Vb[drow * 64 + (((4 | hi) ^ sw) << 3)];
#pragma unroll
      for (int qs = 0; qs < 2; qs++) {
        acc[qs][tt] = MFMA_BF16_16x16x32(pf[qs][0], v0, acc[qs][tt], 0, 0, 0);
        acc[qs][tt] = MFMA_BF16_16x16x32(pf[qs][1], v1, acc[qs][tt], 0, 0, 0);
      }
    }
    __builtin_amdgcn_s_setprio(0);
  };

  bf16x8 kgA[4][2], kgB[4][2];
  stageV(0, V_lds[0]);
  loadK(0, kgA);

  for (int it = 0; it < nt; it += 2) {
    __syncthreads();
    stageV(it + 1, V_lds[1]);
    f32x4 ST0[2][4];
    qkt(kgA, ST0);
    loadK(it + 1, kgB);
    smax(ST0);
    pv(V_lds[0]);

    __syncthreads();
    if (it + 2 < nt) stageV(it + 2, V_lds[0]);
    f32x4 ST1[2][4];
    qkt(kgB, ST1);
    if (it + 2 < nt) loadK(it + 2, kgA);
    smax(ST1);
    pv(V_lds[1]);
  }

#pragma unroll
  for (int qs = 0; qs < 2; qs++) {
    float inv = 1.f / lsum[qs];
    float iv0 = __shfl(inv, hi * 4 + 0);
    float iv1 = __shfl(inv, hi * 4 + 1);
    float iv2 = __shfl(inv, hi * 4 + 2);
    float iv3 = __shfl(inv, hi * 4 + 3);
    float iv[4] = {iv0, iv1, iv2, iv3};
#pragma unroll
    for (int i = 0; i < 4; i++) {
      long row = q0 + qs * 16 + hi * 4 + i;
      __hip_bfloat16* op = out + ((long)b * Nq + row) * 1024 + h * 64 + lo;
#pragma unroll
      for (int tt = 0; tt < 4; tt++) op[tt * 16] = __float2bfloat16(acc[qs][tt][i] * iv[i]);
    }
  }
}

// ------------------------------ launch -------------------------------------

extern "C" void kernel_launch(void* const* d_in, const int* in_sizes, int n_in,
                              void* d_out, int out_size, void* d_ws, size_t ws_size,
                              hipStream_t stream) {
  (void)in_sizes; (void)n_in; (void)out_size; (void)ws_size;

  const float* x      = (const float*)d_in[0];
  const float* ctx    = (const float*)d_in[1];
  const float* rope   = (const float*)d_in[2];
  const float* wqkv   = (const float*)d_in[3];
  const float* sa_qg  = (const float*)d_in[4];
  const float* sa_qb  = (const float*)d_in[5];
  const float* sa_kg  = (const float*)d_in[6];
  const float* sa_kb  = (const float*)d_in[7];
  const float* sa_wo  = (const float*)d_in[8];
  const float* sa_bo  = (const float*)d_in[9];
  const float* ca_wq  = (const float*)d_in[10];
  const float* ca_wk  = (const float*)d_in[11];
  const float* ca_wv  = (const float*)d_in[12];
  const float* ca_qg  = (const float*)d_in[13];
  const float* ca_qb  = (const float*)d_in[14];
  const float* ca_kg  = (const float*)d_in[15];
  const float* ca_kb  = (const float*)d_in[16];
  const float* ca_wo  = (const float*)d_in[17];
  const float* ca_bo  = (const float*)d_in[18];
  const float* ca_gate= (const float*)d_in[19];
  const float* w1g    = (const float*)d_in[20];
  const float* b1g    = (const float*)d_in[21];
  const float* w1x    = (const float*)d_in[22];
  const float* b1x    = (const float*)d_in[23];
  const float* w2     = (const float*)d_in[24];
  const float* b2     = (const float*)d_in[25];
  const float* ls0    = (const float*)d_in[26];
  const float* ls1    = (const float*)d_in[27];
  const float* ls2    = (const float*)d_in[28];

  char* ws = (char*)d_ws;

  // workspace layout (bytes); manual reuse (audited as r20)
  const long OFF_WQKVT = 0;
  const long OFF_SAWOT = 6291456;
  const long OFF_CAWQT = 8388608;
  const long OFF_CAWKT = 10485760;   // ca_wk^T (2 MB), contiguous with
  const long OFF_CAWVT = 12582912;   // ca_wv^T (2 MB) => stacked 2048-row B
  const long OFF_CAWOT = 14680064;
  const long OFF_W1I   = 16777216;   // 16 MB interleaved w1g/w1x
  const long OFF_W2T   = 33554432;
  const long OFF_XB    = 41943040;   // 16 MB (lives to step 6 resid read)
  const long OFF_QC    = OFF_XB;     //   reuse from step 7
  const long OFF_CTXB  = 58720256;
  const long OFF_QKV   = 67108864;   // 48 MB (q,k slices; V slice unwritten)
  const long OFF_CAO   = 67108864;
  const long OFF_X2B   = 83886080;   // 16 MB bf16 x2 (lives to step 16)
  const long OFF_SG    = 100663296;  // 64 MB (8192x4096 bf16, step 14->16)
  const long OFF_SAO   = 117440512;  // SA attn out (dead after step 6)
  const long OFF_KVC   = 117440512;  //   reuse: combined CA K|V (dead after 12)
  const long OFF_CAVT  = 134217728;  // CA V^T swizzled tiled (8 MB)
  const long OFF_X1B   = 167772160;  // 16 MB bf16 x1 (lives to step 13)
  const long OFF_SAVT  = 184549376;  // SA V^T swizzled tiled (16 MB)

  auto bfp = [&](long off) { return (__hip_bfloat16*)(ws + off); };

  dim3 tb32(32, 8);
  // 1. weight transposes
  transpose_cvt<<<dim3(96, 32), tb32, 0, stream>>>(wqkv,  bfp(OFF_WQKVT), 1024, 3072);
  transpose_cvt<<<dim3(32, 32), tb32, 0, stream>>>(sa_wo, bfp(OFF_SAWOT), 1024, 1024);
  transpose_cvt<<<dim3(32, 32), tb32, 0, stream>>>(ca_wq, bfp(OFF_CAWQT), 1024, 1024);
  transpose_cvt<<<dim3(32, 32), tb32, 0, stream>>>(ca_wk, bfp(OFF_CAWKT), 1024, 1024);
  transpose_cvt<<<dim3(32, 32), tb32, 0, stream>>>(ca_wv, bfp(OFF_CAWVT), 1024, 1024);
  transpose_cvt<<<dim3(32, 32), tb32, 0, stream>>>(ca_wo, bfp(OFF_CAWOT), 1024, 1024);
  transpose_cvt_ilv<<<dim3(128, 32), tb32, 0, stream>>>(w1g, bfp(OFF_W1I), 1024, 4096, 0);
  transpose_cvt_ilv<<<dim3(128, 32), tb32, 0, stream>>>(w1x, bfp(OFF_W1I), 1024, 4096, 16);
  transpose_cvt<<<dim3(32, 128), tb32, 0, stream>>>(w2,   bfp(OFF_W2T), 4096, 1024);

  // 2. activations -> bf16
  cvt_f32_bf16<<<8192, 256, 0, stream>>>(x,   bfp(OFF_XB),   8388608);
  cvt_f32_bf16<<<4096, 256, 0, stream>>>(ctx, bfp(OFF_CTXB), 4194304);

  // 3. qkv = xb @ wqkvT + fused SA LN+RoPE (q,k) + swizzled V^T store (EPI=8)
  gemm2ph<128, 8><<<dim3(64, 12), 512, 0, stream>>>(bfp(OFF_XB), bfp(OFF_WQKVT), 8192, 3072, 1024,
                                                    (float*)rope, bfp(OFF_QKV),
                                                    sa_qg, sa_qb, sa_kg, sa_kb, bfp(OFF_SAVT));

  // 5. self-attention -> SAO
  attn32<<<1024, 256, 0, stream>>>(bfp(OFF_QKV),        (long)2048 * 3072, 3072,
                                   bfp(OFF_QKV) + 1024, (long)2048 * 3072, 3072,
                                   bfp(OFF_SAVT), bfp(OFF_SAO), 2048, 2048);

  // 6. sa proj + residual: x1b = bf16( ls0*(sa@wo + bo) + xb )  (resid = XB bf16)
  gemm2ph<128, 1><<<dim3(64, 4), 512, 0, stream>>>(bfp(OFF_SAO), bfp(OFF_SAWOT), 8192, 1024, 1024,
                                                   nullptr, bfp(OFF_X1B), sa_bo, ls0, nullptr, nullptr,
                                                   bfp(OFF_XB));

  // 7. CA q projection + fused LN+RoPE (EPI=9)
  gemm2ph<128, 9><<<dim3(64, 4), 512, 0, stream>>>(bfp(OFF_X1B), bfp(OFF_CAWQT), 8192, 1024, 1024,
                                                   (float*)rope, bfp(OFF_QC),
                                                   ca_qg, ca_qb, nullptr, nullptr, nullptr);
  // 8. CA k|v combined + fused LN on K half + swizzled V^T store (EPI=10)
  gemm2ph<128, 10><<<dim3(32, 8), 512, 0, stream>>>(bfp(OFF_CTXB), bfp(OFF_CAWKT), 4096, 2048, 1024,
                                                    nullptr, bfp(OFF_KVC),
                                                    ca_kg, ca_kb, nullptr, nullptr, bfp(OFF_CAVT));

  // 12. cross-attention (K from KVC, row stride 2048)
  attn32<<<1024, 256, 0, stream>>>(bfp(OFF_QC), (long)2048 * 1024, 1024,
                                   bfp(OFF_KVC), (long)1024 * 2048, 2048,
                                   bfp(OFF_CAVT), bfp(OFF_CAO), 2048, 1024);

  // 13. ca proj: x2b = bf16( ls1*((ca@wo + bo)*tanh(gate)) + x1b )
  gemm2ph<128, 2><<<dim3(64, 4), 512, 0, stream>>>(bfp(OFF_CAO), bfp(OFF_CAWOT), 8192, 1024, 1024,
                                                   nullptr, bfp(OFF_X2B), ca_bo, ls1, ca_gate, nullptr,
                                                   bfp(OFF_X1B));

  // 14. FUSED MLP up: sg = silu(x2b@w1g + b1g) * (x2b@w1x + b1x), EPI=6
  gemm2ph<256, 6><<<dim3(32, 32), 512, 0, stream>>>(bfp(OFF_X2B), bfp(OFF_W1I), 8192, 8192, 1024,
                                                    nullptr, bfp(OFF_SG), b1g, nullptr, b1x, nullptr, nullptr);

  // 16. out = ls2*(sg @ w2T + b2) + x2b   (f32 out)
  gemm2ph<128, 5><<<dim3(64, 4), 512, 0, stream>>>(bfp(OFF_SG), bfp(OFF_W2T), 8192, 1024, 4096,
                                                   (float*)d_out, nullptr, b2, ls2, nullptr, nullptr,
                                                   bfp(OFF_X2B));
}

// Round 23
// 725.476 us; speedup vs baseline: 1.0066x; 1.0066x over previous
//
#include <hip/hip_runtime.h>
#include <hip/hip_bf16.h>
#include <math.h>

// ---------------------------------------------------------------------------
// CrossAttentionBlock on MI355X (gfx950) — FINAL (r20 config, measured 724µs;
// r21's micro-changes were within-noise negative and are reverted).
// Structure: 2-phase BK=64 bf16 MFMA GEMMs (T3-minimum template, 3-bit LDS
// swizzle, setprio) with heavy epilogue fusion: qkv GEMM fuses SA LN+RoPE
// (q,k) and writes V^T swizzled-tiled directly; ca_q fuses LN+RoPE; merged
// CA K|V GEMM fuses K-LN and writes CA V^T; SwiGLU up-proj fused into ONE
// GEMM over 16-wide interleaved weights; bf16 residual chain; attention =
// 4-wave flash kernel with swapped QK^T, in-register softmax (defer-max),
// K register double-buffer, V^T LDS double-buffer, all LDS conflict-free.
// B=4 N=2048 M=1024 C=1024 H=16 HD=64 HID=4096
// ---------------------------------------------------------------------------

typedef __attribute__((ext_vector_type(8))) short bf16x8;   // 8 bf16 in 4 VGPRs
typedef __attribute__((ext_vector_type(4))) short s16x4;    // 4 bf16 (8B)
typedef __attribute__((ext_vector_type(4))) float f32x4;

#define DEV __device__ __forceinline__

DEV unsigned short f2us(float f) {
  __hip_bfloat16 h = __float2bfloat16(f);
  return __builtin_bit_cast(unsigned short, h);
}

DEV short f2us_trunc(float f) {
  return (short)(__builtin_bit_cast(unsigned, f) >> 16);
}

DEV void gload_lds16(const void* g, void* l) {
  __builtin_amdgcn_global_load_lds((const __attribute__((address_space(1))) void*)g,
                                   (__attribute__((address_space(3))) void*)l, 16, 0, 0);
}

#define MFMA_BF16_16x16x32 __builtin_amdgcn_mfma_f32_16x16x32_bf16
#define WAITV0 asm volatile("s_waitcnt vmcnt(0)" ::: "memory")

// ------------------------- elementwise converts ----------------------------

__global__ __launch_bounds__(256) void cvt_f32_bf16(const float* __restrict__ in,
                                                    __hip_bfloat16* __restrict__ out,
                                                    long n) {
  long i = ((long)blockIdx.x * blockDim.x + threadIdx.x) * 4;
  if (i + 3 < n) {
    float4 v = *(const float4*)(in + i);
    out[i + 0] = __float2bfloat16(v.x);
    out[i + 1] = __float2bfloat16(v.y);
    out[i + 2] = __float2bfloat16(v.z);
    out[i + 3] = __float2bfloat16(v.w);
  }
}

// w (K,N) fp32 row-major -> wT (N,K) bf16 row-major
__global__ __launch_bounds__(256) void transpose_cvt(const float* __restrict__ w,
                                                     __hip_bfloat16* __restrict__ wT,
                                                     int K, int N) {
  __shared__ float tile[32][33];
  int n0 = blockIdx.x * 32, k0 = blockIdx.y * 32;
  int tx = threadIdx.x, ty = threadIdx.y;
  #pragma unroll
  for (int i = 0; i < 32; i += 8)
    tile[ty + i][tx] = w[(long)(k0 + ty + i) * N + n0 + tx];
  __syncthreads();
  #pragma unroll
  for (int i = 0; i < 32; i += 8)
    wT[(long)(n0 + ty + i) * K + k0 + tx] = __float2bfloat16(tile[tx][ty + i]);
}

// w (1024, 4096) fp32 -> interleaved-transposed bf16: source col j goes to
// output row r = 32*(j>>4) + (j&15) + ofs  (ofs=0 for w1g, 16 for w1x).
__global__ __launch_bounds__(256) void transpose_cvt_ilv(const float* __restrict__ w,
                                                         __hip_bfloat16* __restrict__ wI,
                                                         int K, int N, int ofs) {
  __shared__ float tile[32][33];
  int n0 = blockIdx.x * 32, k0 = blockIdx.y * 32;
  int tx = threadIdx.x, ty = threadIdx.y;
  #pragma unroll
  for (int i = 0; i < 32; i += 8)
    tile[ty + i][tx] = w[(long)(k0 + ty + i) * N + n0 + tx];
  __syncthreads();
  #pragma unroll
  for (int i = 0; i < 32; i += 8) {
    int j = n0 + ty + i;
    int r = 32 * (j >> 4) + (j & 15) + ofs;
    wI[(long)r * K + k0 + tx] = __float2bfloat16(tile[tx][ty + i]);
  }
}

// --------------------- epilogue helper (simple EPIs) -----------------------
template <int EPI>
DEV void epi_store(long idx, long col, float v,
                   float* __restrict__ out_f, __hip_bfloat16* __restrict__ out_b,
                   const float* __restrict__ bias, const float* __restrict__ scale,
                   const float* __restrict__ gate, const float* __restrict__ resid,
                   const __hip_bfloat16* __restrict__ mulin) {
  if constexpr (EPI == 0) {
    out_b[idx] = __float2bfloat16(v);
  } else if constexpr (EPI == 1) {
    float r = scale[col] * (v + bias[col]) + resid[idx];
    out_b[idx] = __float2bfloat16(r);
  } else if constexpr (EPI == 2) {
    float r = scale[col] * ((v + bias[col]) * tanhf(gate[col])) + __bfloat162float(mulin[idx]);
    out_b[idx] = __float2bfloat16(r);
  } else {  // EPI == 5
    out_f[idx] = scale[col] * (v + bias[col]) + __bfloat162float(mulin[idx]);
  }
}

// --------------- GEMM BMx256, BK=64, 2-phase (T3 minimum, r5) --------------
// EPI=6: fused SwiGLU over 16-wide interleaved W1I cols (out ld N/2).
// EPI=8 (qkv): slice0=q LN+rope, slice1=k LN+rope, slice2=v -> swizzled V^T
//              tiled store (vt via mulin, 8192B tiles, granule ^= drow&7).
// EPI=9 (ca_q): LN+rope. EPI=10 (kvc): slice0=K LN no rope, slice1=V -> V^T.
template <int BM, int EPI>
__global__ __launch_bounds__(512, 2) void gemm2ph(const __hip_bfloat16* __restrict__ A,
                                                  const __hip_bfloat16* __restrict__ Bt,
                                                  int M, int N, int K,
                                                  float* __restrict__ out_f,
                                                  __hip_bfloat16* __restrict__ out_b,
                                                  const float* __restrict__ bias,
                                                  const float* __restrict__ scale,
                                                  const float* __restrict__ gate,
                                                  const float* __restrict__ resid,
                                                  const __hip_bfloat16* __restrict__ mulin) {
  constexpr int MF = BM / 32;
  constexpr int WRS = BM / 2;
  constexpr int AJ = BM * 8 / 512;
  __shared__ __align__(16) unsigned short As[2][BM * 64];
  __shared__ __align__(16) unsigned short Bs[2][256 * 64];

  int t = threadIdx.x;
  int l = t & 63, w = t >> 6;
  int lo = l & 15, hi = l >> 4;
  int wr = w >> 2, wc = w & 3;
  long bm = blockIdx.x, bn = blockIdx.y;
  const __hip_bfloat16* Ab = A + bm * BM * (long)K;
  const __hip_bfloat16* Bb = Bt + bn * 256 * (long)K;
  int nt = K >> 6;

  auto stage = [&](int kt, int buf) {
    long kb = (long)kt * 64;
    #pragma unroll
    for (int j = 0; j < AJ; j++) {
      int q = j * 512 + t;
      int row = q >> 3, c = (q & 7) ^ (row & 7);
      gload_lds16(Ab + (long)row * K + kb + c * 8, &As[buf][q * 8]);
    }
    #pragma unroll
    for (int j = 0; j < 4; j++) {
      int q = j * 512 + t;
      int row = q >> 3, c = (q & 7) ^ (row & 7);
      gload_lds16(Bb + (long)row * K + kb + c * 8, &Bs[buf][q * 8]);
    }
  };

  f32x4 acc[MF][4] = {};

  stage(0, 0);
  WAITV0;
  __builtin_amdgcn_s_barrier();

  for (int kt = 0; kt < nt; ++kt) {
    int cur = kt & 1;
    if (kt + 1 < nt) stage(kt + 1, cur ^ 1);

    #pragma unroll
    for (int ks = 0; ks < 2; ks++) {
      bf16x8 bfrag[4];
      #pragma unroll
      for (int n = 0; n < 4; n++) {
        int rb = wc * 64 + n * 16 + lo;
        bfrag[n] = *(const bf16x8*)&Bs[cur][rb * 64 + (((ks << 2) | hi) ^ (rb & 7)) * 8];
      }
      #pragma unroll
      for (int mg = 0; mg < MF; mg += 4) {
        bf16x8 afrag[4];
        #pragma unroll
        for (int m = 0; m < 4; m++) {
          int ra = wr * WRS + (mg + m) * 16 + lo;
          afrag[m] = *(const bf16x8*)&As[cur][ra * 64 + (((ks << 2) | hi) ^ (ra & 7)) * 8];
        }
        __builtin_amdgcn_s_setprio(1);
        #pragma unroll
        for (int m = 0; m < 4; m++)
          #pragma unroll
          for (int n = 0; n < 4; n++)
            acc[mg + m][n] = MFMA_BF16_16x16x32(afrag[m], bfrag[n], acc[mg + m][n], 0, 0, 0);
        __builtin_amdgcn_s_setprio(0);
      }
    }

    if (kt + 1 < nt) {
      WAITV0;
      __builtin_amdgcn_s_barrier();
    }
  }

  if constexpr (EPI == 6) {
    #pragma unroll
    for (int m = 0; m < MF; m++)
      #pragma unroll
      for (int np = 0; np < 2; np++)
        #pragma unroll
        for (int i = 0; i < 4; i++) {
          long row = bm * BM + wr * WRS + m * 16 + hi * 4 + i;
          long jc = bn * 128 + wc * 32 + np * 16 + lo;
          float g = acc[m][np * 2][i] + bias[jc];
          float xv = acc[m][np * 2 + 1][i] + gate[jc];
          float hv = (g / (1.f + expf(-g))) * xv;
          out_b[row * (long)(N >> 1) + jc] = __float2bfloat16(hv);
        }
  } else if constexpr (EPI == 8 || EPI == 9 || EPI == 10) {
    int colbase = (int)(bn * 256 + wc * 64);   // wave-uniform; spans one head
    int slice = colbase >> 10;
    bool dovt = (EPI == 8 && slice == 2) || (EPI == 10 && slice == 1);
    if (dovt) {
      // Swizzled V^T tiled store: [b*16+h][kvtile][drow=nn*16+lo][64 shorts],
      // 16B granule gk=2m+(hi>>1) ^ (drow&7), 8B half = hi&1.
      unsigned short* vt = (unsigned short*)mulin;
      int h = (colbase >> 6) & 15;
      int kvt = (EPI == 8) ? ((int)(bm & 15) * 2 + wr) : ((int)(bm & 7) * 2 + wr);
      constexpr int NTV = (EPI == 8) ? 32 : 16;
      #pragma unroll
      for (int m = 0; m < MF; m++) {
        long row0 = bm * BM + wr * WRS + m * 16 + hi * 4;   // i=0 token row
        int b = (int)(row0 >> ((EPI == 8) ? 11 : 10));
        long tb = ((long)(b * 16 + h) * NTV + kvt) * 4096;  // 8192B tiles
        int gk = 2 * m + (hi >> 1);
        #pragma unroll
        for (int nn = 0; nn < 4; nn++) {
          int drow = nn * 16 + lo;
          s16x4 pw;
          pw[0] = (short)f2us(acc[m][nn][0]);
          pw[1] = (short)f2us(acc[m][nn][1]);
          pw[2] = (short)f2us(acc[m][nn][2]);
          pw[3] = (short)f2us(acc[m][nn][3]);
          long off = tb + (long)drow * 64 + (((gk ^ (drow & 7)) << 3) | ((hi & 1) << 2));
          *(s16x4*)&vt[off] = pw;
        }
      }
    } else {
      const float *gv_p, *bv_p;
      if constexpr (EPI == 8) {
        gv_p = (slice == 0) ? bias : gate;       // sa_qg : sa_kg
        bv_p = (slice == 0) ? scale : resid;     // sa_qb : sa_kb
      } else if constexpr (EPI == 9) {
        gv_p = bias; bv_p = scale;               // ca_qg, ca_qb
      } else {
        gv_p = bias; bv_p = scale;               // ca_kg, ca_kb (slice 0)
      }
      float gv[4], bv[4];
      #pragma unroll
      for (int nn = 0; nn < 4; nn++) {
        gv[nn] = gv_p[nn * 16 + lo];
        bv[nn] = bv_p[nn * 16 + lo];
      }
      #pragma unroll
      for (int m = 0; m < MF; m++)
        #pragma unroll
        for (int i = 0; i < 4; i++) {
          float v0 = acc[m][0][i], v1 = acc[m][1][i], v2 = acc[m][2][i], v3 = acc[m][3][i];
          float s = (v0 + v1) + (v2 + v3);
          s += __shfl_xor(s, 1); s += __shfl_xor(s, 2);
          s += __shfl_xor(s, 4); s += __shfl_xor(s, 8);
          float mean = s * 0.015625f;
          float d0 = v0 - mean, d1 = v1 - mean, d2 = v2 - mean, d3 = v3 - mean;
          float q2 = (d0 * d0 + d1 * d1) + (d2 * d2 + d3 * d3);
          q2 += __shfl_xor(q2, 1); q2 += __shfl_xor(q2, 2);
          q2 += __shfl_xor(q2, 4); q2 += __shfl_xor(q2, 8);
          float rstd = rsqrtf(q2 * 0.015625f + 1e-6f);
          long row = bm * BM + wr * WRS + m * 16 + hi * 4 + i;
          int nseq = (int)(row & 2047);        // rows = b*2048 + n (M=8192)
          float xsv[4] = {d0 * rstd, d1 * rstd, d2 * rstd, d3 * rstd};
          #pragma unroll
          for (int nn = 0; nn < 4; nn++) {
            float xn = xsv[nn] * gv[nn] + bv[nn];
            if constexpr (EPI != 10) {         // rope (EPI 8/9)
              float partner = __shfl_xor(xn, 1);
              int d = nn * 16 + lo;
              float sn = out_f[(long)nseq * 128 + d];
              float cs = out_f[(long)nseq * 128 + 64 + d];
              xn = (lo & 1) ? (xn * cs + partner * sn) : (xn * cs - partner * sn);
            }
            out_b[row * (long)N + colbase + nn * 16 + lo] = __float2bfloat16(xn);
          }
        }
    }
  } else {
    #pragma unroll
    for (int m = 0; m < MF; m++)
      #pragma unroll
      for (int n = 0; n < 4; n++)
        #pragma unroll
        for (int i = 0; i < 4; i++) {
          long row = bm * BM + wr * WRS + m * 16 + hi * 4 + i;
          long col = bn * 256 + wc * 64 + n * 16 + lo;
          epi_store<EPI>(row * (long)N + col, col, acc[m][n][i],
                         out_f, out_b, bias, scale, gate, resid, mulin);
        }
  }
}

// ---------------------------- attention ------------------------------------
// r7 structure + T5 setprio; V^T and P in the GEMM-proven swizzled layout
// (64-short rows, 16B granule ^= row&7 -> ~0 ds_read conflicts).
__global__ __launch_bounds__(256) void attn32(const __hip_bfloat16* __restrict__ qB, long qBatch, long qRow,
                                              const __hip_bfloat16* __restrict__ kB, long kBatch, long kRow,
                                              const __hip_bfloat16* __restrict__ vt,
                                              __hip_bfloat16* __restrict__ out, int Nq, int Nkv) {
  const float SC2 = 0.125f * 1.44269504089f;
  int t = threadIdx.x;
  int l = t & 63, w = t >> 6;
  int lo = l & 15, hi = l >> 4;
  int nQC = Nq >> 7;
  int qc = blockIdx.x % nQC;
  int bh = blockIdx.x / nQC;
  int h = bh & 15, b = bh >> 4;
  int q0 = qc * 128 + w * 32;

  __shared__ unsigned short P_all[4][32 * 64];   // swizzled, per-wave
  __shared__ unsigned short V_lds[2][64 * 64];   // swizzled tile copy
  unsigned short* P = P_all[w];

  bf16x8 qf[2][2];
#pragma unroll
  for (int qs = 0; qs < 2; qs++) {
    const __hip_bfloat16* qp = qB + (long)b * qBatch + (long)(q0 + qs * 16 + lo) * qRow + h * 64 + hi * 8;
    qf[qs][0] = *(const bf16x8*)qp;
    qf[qs][1] = *(const bf16x8*)(qp + 32);
  }

  float mrow[2] = {-INFINITY, -INFINITY};
  float lsum[2] = {0.f, 0.f};
  f32x4 acc[2][4] = {};
  const f32x4 fz = {0.f, 0.f, 0.f, 0.f};

  const __hip_bfloat16* kbase = kB + (long)b * kBatch + h * 64 + hi * 8;
  int nt = Nkv >> 6;
  const char* vtb = (const char*)vt + (long)bh * nt * 8192;

  auto stageV = [&](int tile, unsigned short* dstb) {
    const char* src = vtb + (long)tile * 8192;
    gload_lds16(src + t * 16, &dstb[t * 8]);
    gload_lds16(src + (t + 256) * 16, &dstb[(t + 256) * 8]);
  };
  auto loadK = [&](int tile, bf16x8 (&kg)[4][2]) {
#pragma unroll
    for (int g = 0; g < 4; g++) {
      const __hip_bfloat16* kp = kbase + (long)(tile * 64 + g * 16 + lo) * kRow;
      kg[g][0] = *(const bf16x8*)kp;
      kg[g][1] = *(const bf16x8*)(kp + 32);
    }
  };
  auto qkt = [&](bf16x8 (&kg)[4][2], f32x4 (&ST)[2][4]) {
    __builtin_amdgcn_s_setprio(1);
#pragma unroll
    for (int qs = 0; qs < 2; qs++)
#pragma unroll
      for (int g = 0; g < 4; g++) {
        f32x4 s0 = MFMA_BF16_16x16x32(kg[g][0], qf[qs][0], fz, 0, 0, 0);
        ST[qs][g] = MFMA_BF16_16x16x32(kg[g][1], qf[qs][1], s0, 0, 0, 0);
      }
    __builtin_amdgcn_s_setprio(0);
  };
  auto smax = [&](f32x4 (&ST)[2][4]) {
#pragma unroll
    for (int qs = 0; qs < 2; qs++) {
      float mg0 = fmaxf(fmaxf(ST[qs][0][0], ST[qs][0][1]), fmaxf(ST[qs][0][2], ST[qs][0][3]));
      float mg1 = fmaxf(fmaxf(ST[qs][1][0], ST[qs][1][1]), fmaxf(ST[qs][1][2], ST[qs][1][3]));
      float mg2 = fmaxf(fmaxf(ST[qs][2][0], ST[qs][2][1]), fmaxf(ST[qs][2][2], ST[qs][2][3]));
      float mg3 = fmaxf(fmaxf(ST[qs][3][0], ST[qs][3][1]), fmaxf(ST[qs][3][2], ST[qs][3][3]));
      float rm = fmaxf(fmaxf(mg0, mg1), fmaxf(mg2, mg3)) * SC2;
      rm = fmaxf(rm, __shfl_xor(rm, 16));
      rm = fmaxf(rm, __shfl_xor(rm, 32));
      if (!__all(rm <= mrow[qs] + 8.f)) {     // defer-max (T13)
        float mn = fmaxf(mrow[qs], rm);
        float scl = exp2f(mrow[qs] - mn);
        mrow[qs] = mn;
        lsum[qs] *= scl;
        float c0 = __shfl(scl, hi * 4 + 0);
        float c1 = __shfl(scl, hi * 4 + 1);
        float c2 = __shfl(scl, hi * 4 + 2);
        float c3 = __shfl(scl, hi * 4 + 3);
#pragma unroll
        for (int tt = 0; tt < 4; tt++) {
          acc[qs][tt][0] *= c0; acc[qs][tt][1] *= c1;
          acc[qs][tt][2] *= c2; acc[qs][tt][3] *= c3;
        }
      }
      float m = mrow[qs];
      float rs = 0.f;
      int qrow = qs * 16 + lo;
      int sw = lo & 7;
#pragma unroll
      for (int g = 0; g < 4; g++) {
        float p0 = exp2f(fmaf(ST[qs][g][0], SC2, -m));
        float p1 = exp2f(fmaf(ST[qs][g][1], SC2, -m));
        float p2 = exp2f(fmaf(ST[qs][g][2], SC2, -m));
        float p3 = exp2f(fmaf(ST[qs][g][3], SC2, -m));
        rs += (p0 + p1) + (p2 + p3);
        s16x4 pw;
        pw[0] = f2us_trunc(p0); pw[1] = f2us_trunc(p1);
        pw[2] = f2us_trunc(p2); pw[3] = f2us_trunc(p3);
        int gk = 2 * g + (hi >> 1);
        *(s16x4*)&P[qrow * 64 + (((gk ^ sw) << 3) | ((hi & 1) << 2))] = pw;
      }
      rs += __shfl_xor(rs, 16);
      rs += __shfl_xor(rs, 32);
      lsum[qs] += rs;
    }
  };
  auto pv = [&](const unsigned short* Vb) {
    bf16x8 pf[2][2];
    int sw = lo & 7;
#pragma unroll
    for (int qs = 0; qs < 2; qs++) {
      int qrow = qs * 16 + lo;
      pf[qs][0] = *(const bf16x8*)&P[qrow * 64 + ((hi ^ sw) << 3)];
      pf[qs][1] = *(const bf16x8*)&P[qrow * 64 + (((4 | hi) ^ sw) << 3)];
    }
    __builtin_amdgcn_s_setprio(1);
#pragma unroll
    for (int tt = 0; tt < 4; tt++) {
      int drow = tt * 16 + lo;
      bf16x8 v0 = *(const bf16x8*)&Vb[drow * 64 + ((hi ^ sw) << 3)];
      bf16x8 v1 = *(const bf16x8*)&Vb[drow * 64 + (((4 | hi) ^ sw) << 3)];
#pragma unroll
      for (int qs = 0; qs < 2; qs++) {
        acc[qs][tt] = MFMA_BF16_16x16x32(pf[qs][0], v0, acc[qs][tt], 0, 0, 0);
        acc[qs][tt] = MFMA_BF16_16x16x32(pf[qs][1], v1, acc[qs][tt], 0, 0, 0);
      }
    }
    __builtin_amdgcn_s_setprio(0);
  };

  bf16x8 kgA[4][2], kgB[4][2];
  stageV(0, V_lds[0]);
  loadK(0, kgA);

  for (int it = 0; it < nt; it += 2) {
    __syncthreads();
    stageV(it + 1, V_lds[1]);
    f32x4 ST0[2][4];
    qkt(kgA, ST0);
    loadK(it + 1, kgB);
    smax(ST0);
    pv(V_lds[0]);

    __syncthreads();
    if (it + 2 < nt) stageV(it + 2, V_lds[0]);
    f32x4 ST1[2][4];
    qkt(kgB, ST1);
    if (it + 2 < nt) loadK(it + 2, kgA);
    smax(ST1);
    pv(V_lds[1]);
  }

#pragma unroll
  for (int qs = 0; qs < 2; qs++) {
    float inv = 1.f / lsum[qs];
    float iv0 = __shfl(inv, hi * 4 + 0);
    float iv1 = __shfl(inv, hi * 4 + 1);
    float iv2 = __shfl(inv, hi * 4 + 2);
    float iv3 = __shfl(inv, hi * 4 + 3);
    float iv[4] = {iv0, iv1, iv2, iv3};
#pragma unroll
    for (int i = 0; i < 4; i++) {
      long row = q0 + qs * 16 + hi * 4 + i;
      __hip_bfloat16* op = out + ((long)b * Nq + row) * 1024 + h * 64 + lo;
#pragma unroll
      for (int tt = 0; tt < 4; tt++) op[tt * 16] = __float2bfloat16(acc[qs][tt][i] * iv[i]);
    }
  }
}

// ------------------------------ launch -------------------------------------

extern "C" void kernel_launch(void* const* d_in, const int* in_sizes, int n_in,
                              void* d_out, int out_size, void* d_ws, size_t ws_size,
                              hipStream_t stream) {
  (void)in_sizes; (void)n_in; (void)out_size; (void)ws_size;

  const float* x      = (const float*)d_in[0];
  const float* ctx    = (const float*)d_in[1];
  const float* rope   = (const float*)d_in[2];
  const float* wqkv   = (const float*)d_in[3];
  const float* sa_qg  = (const float*)d_in[4];
  const float* sa_qb  = (const float*)d_in[5];
  const float* sa_kg  = (const float*)d_in[6];
  const float* sa_kb  = (const float*)d_in[7];
  const float* sa_wo  = (const float*)d_in[8];
  const float* sa_bo  = (const float*)d_in[9];
  const float* ca_wq  = (const float*)d_in[10];
  const float* ca_wk  = (const float*)d_in[11];
  const float* ca_wv  = (const float*)d_in[12];
  const float* ca_qg  = (const float*)d_in[13];
  const float* ca_qb  = (const float*)d_in[14];
  const float* ca_kg  = (const float*)d_in[15];
  const float* ca_kb  = (const float*)d_in[16];
  const float* ca_wo  = (const float*)d_in[17];
  const float* ca_bo  = (const float*)d_in[18];
  const float* ca_gate= (const float*)d_in[19];
  const float* w1g    = (const float*)d_in[20];
  const float* b1g    = (const float*)d_in[21];
  const float* w1x    = (const float*)d_in[22];
  const float* b1x    = (const float*)d_in[23];
  const float* w2     = (const float*)d_in[24];
  const float* b2     = (const float*)d_in[25];
  const float* ls0    = (const float*)d_in[26];
  const float* ls1    = (const float*)d_in[27];
  const float* ls2    = (const float*)d_in[28];

  char* ws = (char*)d_ws;

  // workspace layout (bytes); manual reuse (audited)
  const long OFF_WQKVT = 0;
  const long OFF_SAWOT = 6291456;
  const long OFF_CAWQT = 8388608;
  const long OFF_CAWKT = 10485760;   // ca_wk^T (2 MB), contiguous with
  const long OFF_CAWVT = 12582912;   // ca_wv^T (2 MB) => stacked 2048-row B
  const long OFF_CAWOT = 14680064;
  const long OFF_W1I   = 16777216;   // 16 MB interleaved w1g/w1x
  const long OFF_W2T   = 33554432;
  const long OFF_XB    = 41943040;   // 16 MB (dead after qkv gemm)
  const long OFF_QC    = OFF_XB;     //   reuse
  const long OFF_CTXB  = 58720256;
  const long OFF_QKV   = 67108864;   // 48 MB (q,k slices; V slice unwritten)
  const long OFF_CAO   = 67108864;
  const long OFF_X2B   = 83886080;   // 16 MB bf16 x2 (lives to step 16)
  const long OFF_SG    = 100663296;  // 64 MB (8192x4096 bf16, step 14->16)
  const long OFF_SAO   = 117440512;  // SA attn out (dead after step 6)
  const long OFF_KVC   = 117440512;  //   reuse: combined CA K|V (dead after 12)
  const long OFF_CAVT  = 134217728;  // CA V^T swizzled tiled (8 MB)
  const long OFF_X1B   = 167772160;  // 16 MB bf16 x1 (lives to step 13)
  const long OFF_SAVT  = 184549376;  // SA V^T swizzled tiled (16 MB)

  auto bfp = [&](long off) { return (__hip_bfloat16*)(ws + off); };

  dim3 tb32(32, 8);
  // 1. weight transposes
  transpose_cvt<<<dim3(96, 32), tb32, 0, stream>>>(wqkv,  bfp(OFF_WQKVT), 1024, 3072);
  transpose_cvt<<<dim3(32, 32), tb32, 0, stream>>>(sa_wo, bfp(OFF_SAWOT), 1024, 1024);
  transpose_cvt<<<dim3(32, 32), tb32, 0, stream>>>(ca_wq, bfp(OFF_CAWQT), 1024, 1024);
  transpose_cvt<<<dim3(32, 32), tb32, 0, stream>>>(ca_wk, bfp(OFF_CAWKT), 1024, 1024);
  transpose_cvt<<<dim3(32, 32), tb32, 0, stream>>>(ca_wv, bfp(OFF_CAWVT), 1024, 1024);
  transpose_cvt<<<dim3(32, 32), tb32, 0, stream>>>(ca_wo, bfp(OFF_CAWOT), 1024, 1024);
  transpose_cvt_ilv<<<dim3(128, 32), tb32, 0, stream>>>(w1g, bfp(OFF_W1I), 1024, 4096, 0);
  transpose_cvt_ilv<<<dim3(128, 32), tb32, 0, stream>>>(w1x, bfp(OFF_W1I), 1024, 4096, 16);
  transpose_cvt<<<dim3(32, 128), tb32, 0, stream>>>(w2,   bfp(OFF_W2T), 4096, 1024);

  // 2. activations -> bf16
  cvt_f32_bf16<<<8192, 256, 0, stream>>>(x,   bfp(OFF_XB),   8388608);
  cvt_f32_bf16<<<4096, 256, 0, stream>>>(ctx, bfp(OFF_CTXB), 4194304);

  // 3. qkv = xb @ wqkvT + fused SA LN+RoPE (q,k) + swizzled V^T store (EPI=8)
  gemm2ph<128, 8><<<dim3(64, 12), 512, 0, stream>>>(bfp(OFF_XB), bfp(OFF_WQKVT), 8192, 3072, 1024,
                                                    (float*)rope, bfp(OFF_QKV),
                                                    sa_qg, sa_qb, sa_kg, sa_kb, bfp(OFF_SAVT));

  // 5. self-attention -> SAO
  attn32<<<1024, 256, 0, stream>>>(bfp(OFF_QKV),        (long)2048 * 3072, 3072,
                                   bfp(OFF_QKV) + 1024, (long)2048 * 3072, 3072,
                                   bfp(OFF_SAVT), bfp(OFF_SAO), 2048, 2048);

  // 6. sa proj + residual: x1b = bf16( ls0*(sa@wo + bo) + x )
  gemm2ph<128, 1><<<dim3(64, 4), 512, 0, stream>>>(bfp(OFF_SAO), bfp(OFF_SAWOT), 8192, 1024, 1024,
                                                   nullptr, bfp(OFF_X1B), sa_bo, ls0, nullptr, x, nullptr);

  // 7. CA q projection + fused LN+RoPE (EPI=9)
  gemm2ph<128, 9><<<dim3(64, 4), 512, 0, stream>>>(bfp(OFF_X1B), bfp(OFF_CAWQT), 8192, 1024, 1024,
                                                   (float*)rope, bfp(OFF_QC),
                                                   ca_qg, ca_qb, nullptr, nullptr, nullptr);
  // 8. CA k|v combined + fused LN on K half + swizzled V^T store (EPI=10)
  gemm2ph<128, 10><<<dim3(32, 8), 512, 0, stream>>>(bfp(OFF_CTXB), bfp(OFF_CAWKT), 4096, 2048, 1024,
                                                    nullptr, bfp(OFF_KVC),
                                                    ca_kg, ca_kb, nullptr, nullptr, bfp(OFF_CAVT));

  // 12. cross-attention (K from KVC, row stride 2048)
  attn32<<<1024, 256, 0, stream>>>(bfp(OFF_QC), (long)2048 * 1024, 1024,
                                   bfp(OFF_KVC), (long)1024 * 2048, 2048,
                                   bfp(OFF_CAVT), bfp(OFF_CAO), 2048, 1024);

  // 13. ca proj: x2b = bf16( ls1*((ca@wo + bo)*tanh(gate)) + x1b )
  gemm2ph<128, 2><<<dim3(64, 4), 512, 0, stream>>>(bfp(OFF_CAO), bfp(OFF_CAWOT), 8192, 1024, 1024,
                                                   nullptr, bfp(OFF_X2B), ca_bo, ls1, ca_gate, nullptr,
                                                   bfp(OFF_X1B));

  // 14. FUSED MLP up: sg = silu(x2b@w1g + b1g) * (x2b@w1x + b1x), EPI=6
  gemm2ph<256, 6><<<dim3(32, 32), 512, 0, stream>>>(bfp(OFF_X2B), bfp(OFF_W1I), 8192, 8192, 1024,
                                                    nullptr, bfp(OFF_SG), b1g, nullptr, b1x, nullptr, nullptr);

  // 16. out = ls2*(sg @ w2T + b2) + x2b   (f32 out)
  gemm2ph<128, 5><<<dim3(64, 4), 512, 0, stream>>>(bfp(OFF_SG), bfp(OFF_W2T), 8192, 1024, 4096,
                                                   (float*)d_out, nullptr, b2, ls2, nullptr, nullptr,
                                                   bfp(OFF_X2B));
}